// Round 1
// baseline (99.513 us; speedup 1.0000x reference)
//
#include <hip/hip_runtime.h>

// Quantum circuit simulator: 12 wires, DIM=4096, 3 layers, batch=512.
// One block per batch element; full complex state lives in LDS (re/im planes).
// Per layer: 12 single-qubit gates (pair updates, 1 barrier each) + the 11-CNOT
// chain fused into a single gather permutation (2 barriers). Measurement fused
// into a single weighted-probability reduction.

namespace {

constexpr int N_WIRES  = 12;
constexpr int DIM      = 1 << N_WIRES;      // 4096
constexpr int N_LAYERS = 3;
constexpr int THREADS  = 256;
constexpr int PER      = DIM / THREADS;     // 16 amplitudes per thread
constexpr int PPT      = (DIM / 2) / THREADS; // 8 gate-pairs per thread
constexpr int NGATES   = N_LAYERS * N_WIRES;  // 36

__global__ __launch_bounds__(THREADS)
void qcirc_kernel(const float* __restrict__ state,
                  const float* __restrict__ weights,
                  const float* __restrict__ head_w,
                  const float* __restrict__ head_b,
                  float* __restrict__ out)
{
    __shared__ float re[DIM];
    __shared__ float im[DIM];
    __shared__ float Umat[NGATES][8];
    __shared__ float redbuf[THREADS / 64];

    const int tid = threadIdx.x;
    const int b   = blockIdx.x;

    // ---- Precompute all 36 gate matrices (one thread each). U = RZ(c)RY(b)RX(a).
    // SU(2) structure: U = [[u00, -conj(u10)], [u10, conj(u00)]].
    if (tid < NGATES) {
        const float* wp = weights + tid * 3;
        float ha = 0.5f * wp[0], hb = 0.5f * wp[1], hc = 0.5f * wp[2];
        float ca = cosf(ha), sa = sinf(ha);
        float cb = cosf(hb), sb = sinf(hb);
        float ecr = cosf(hc), eci = -sinf(hc);   // ec = e^{-i c/2}
        float t0 = cb * ca, t1 = sb * sa, t2 = sb * ca, t3 = cb * sa;
        float u00r =  ecr * t0 - eci * t1;       // ec * (t0 + i t1)
        float u00i =  ecr * t1 + eci * t0;
        float u10r =  ecr * t2 - eci * t3;       // conj(ec) * (t2 - i t3)
        float u10i = -ecr * t3 - eci * t2;
        Umat[tid][0] =  u00r;   // U00
        Umat[tid][1] =  u00i;
        Umat[tid][2] = -u10r;   // U01 = -conj(U10)
        Umat[tid][3] =  u10i;
        Umat[tid][4] =  u10r;   // U10
        Umat[tid][5] =  u10i;
        Umat[tid][6] =  u00r;   // U11 = conj(U00)
        Umat[tid][7] = -u00i;
    }

    // ---- Load initial state (real amplitudes), zero imaginary plane.
    {
        const float4* s4 = reinterpret_cast<const float4*>(state + (size_t)b * DIM);
        #pragma unroll
        for (int k = 0; k < PER / 4; ++k) {
            int i4 = tid + k * THREADS;
            float4 v = s4[i4];
            int base = i4 * 4;
            re[base + 0] = v.x; re[base + 1] = v.y;
            re[base + 2] = v.z; re[base + 3] = v.w;
            im[base + 0] = 0.f; im[base + 1] = 0.f;
            im[base + 2] = 0.f; im[base + 3] = 0.f;
        }
    }

    for (int l = 0; l < N_LAYERS; ++l) {
        // ---- 12 single-qubit gates
        for (int w = 0; w < N_WIRES; ++w) {
            __syncthreads();
            const float* U = Umat[l * N_WIRES + w];   // LDS broadcast reads
            float u00r = U[0], u00i = U[1], u01r = U[2], u01i = U[3];
            float u10r = U[4], u10i = U[5], u11r = U[6], u11i = U[7];
            const int sh = N_WIRES - 1 - w;           // wire w -> bit (11-w)
            const int dr = 1 << sh;
            #pragma unroll
            for (int k = 0; k < PPT; ++k) {
                int p  = tid + k * THREADS;           // pair index 0..2047
                int hi = p >> sh;
                int lo = p & (dr - 1);
                int i0 = (hi << (sh + 1)) | lo;
                int i1 = i0 + dr;
                float r0 = re[i0], m0 = im[i0];
                float r1 = re[i1], m1 = im[i1];
                re[i0] = u00r * r0 - u00i * m0 + u01r * r1 - u01i * m1;
                im[i0] = u00r * m0 + u00i * r0 + u01r * m1 + u01i * r1;
                re[i1] = u10r * r0 - u10i * m0 + u11r * r1 - u11i * m1;
                im[i1] = u10r * m0 + u10i * r0 + u11r * m1 + u11i * r1;
            }
        }

        // ---- Fused CNOT chain: psi'[i] = psi[perm(i)].
        // Chain w=0..10 applied in order composes to: start j=i, then for
        // w = 10..0: if bit(11-w) of j set, flip bit(10-w).
        __syncthreads();
        float tr[PER], ti[PER];
        #pragma unroll
        for (int k = 0; k < PER; ++k) {
            int i = tid + k * THREADS;
            int j = i;
            #pragma unroll
            for (int w = N_WIRES - 2; w >= 0; --w)
                j ^= ((j >> (N_WIRES - 1 - w)) & 1) << (N_WIRES - 2 - w);
            tr[k] = re[j];
            ti[k] = im[j];
        }
        __syncthreads();
        #pragma unroll
        for (int k = 0; k < PER; ++k) {
            int i = tid + k * THREADS;
            re[i] = tr[k];
            im[i] = ti[k];
        }
    }

    // ---- Measurement: out[b] = head_b + sum_i |psi_i|^2 * c_i,
    //      c_i = sum_w head_w[w] * (1 - 2*bit_{11-w}(i))
    __syncthreads();
    float hw[N_WIRES];
    #pragma unroll
    for (int w = 0; w < N_WIRES; ++w) hw[w] = head_w[w];

    float acc = 0.f;
    #pragma unroll
    for (int k = 0; k < PER; ++k) {
        int i = tid + k * THREADS;
        float p = re[i] * re[i] + im[i] * im[i];
        float c = 0.f;
        #pragma unroll
        for (int w = 0; w < N_WIRES; ++w)
            c += ((i >> (N_WIRES - 1 - w)) & 1) ? -hw[w] : hw[w];
        acc += p * c;
    }

    // wave (64-lane) shuffle reduce, then cross-wave via LDS
    #pragma unroll
    for (int off = 32; off > 0; off >>= 1)
        acc += __shfl_down(acc, off, 64);
    if ((tid & 63) == 0) redbuf[tid >> 6] = acc;
    __syncthreads();
    if (tid == 0) {
        float s = 0.f;
        #pragma unroll
        for (int q = 0; q < THREADS / 64; ++q) s += redbuf[q];
        out[b] = s + head_b[0];
    }
}

} // namespace

extern "C" void kernel_launch(void* const* d_in, const int* in_sizes, int n_in,
                              void* d_out, int out_size, void* d_ws, size_t ws_size,
                              hipStream_t stream)
{
    const float* state   = (const float*)d_in[0];  // (B, 4096) fp32
    const float* weights = (const float*)d_in[1];  // (3, 12, 3) fp32
    const float* head_w  = (const float*)d_in[2];  // (1, 12) fp32
    const float* head_b  = (const float*)d_in[3];  // (1,) fp32
    float* out = (float*)d_out;                    // (B,) fp32

    const int batch = in_sizes[0] / DIM;           // 512
    qcirc_kernel<<<batch, THREADS, 0, stream>>>(state, weights, head_w, head_b, out);
}

// Round 2
// 87.181 us; speedup vs baseline: 1.1415x; 1.1415x over previous
//
#include <hip/hip_runtime.h>

// Quantum circuit simulator: 12 wires, DIM=4096, 3 layers, batch=512.
// R2 design: register-blocked gate groups + algebraic CNOT folding.
//  - Each thread owns 16 complex amps in registers; 12 gates/layer applied as
//    3 groups of 4 in-register gates (target bits live in the k-index).
//  - LDS only remaps data between groups (3 round trips/layer, padded
//    float2 layout idx=i+(i>>4) -> conflict-free for all phases).
//  - The 11-CNOT chain composes to the LINEAR map perm(i) = i ^ (i>>1)
//    (binary->Gray). It is folded into the next layer's gather addresses;
//    the final perm folds into the measurement weight via inverse-Gray.
//  - Barriers: 11 total (vs 42 in R1).

namespace {

constexpr int N_WIRES  = 12;
constexpr int DIM      = 1 << N_WIRES;        // 4096
constexpr int N_LAYERS = 3;
constexpr int THREADS  = 256;
constexpr int PER      = DIM / THREADS;       // 16 amps/thread
constexpr int NGATES   = N_LAYERS * N_WIRES;  // 36
constexpr int PADDED   = DIM + (DIM >> 4);    // 4352 float2 slots

__device__ __forceinline__ void apply4(float ar[PER], float ai[PER],
                                       const float (*Um)[8], int gbase)
{
    #pragma unroll
    for (int gg = 0; gg < 4; ++gg) {
        const float4 uA = *reinterpret_cast<const float4*>(&Um[gbase + gg][0]);
        const float4 uB = *reinterpret_cast<const float4*>(&Um[gbase + gg][4]);
        const float u00r = uA.x, u00i = uA.y, u01r = uA.z, u01i = uA.w;
        const float u10r = uB.x, u10i = uB.y, u11r = uB.z, u11i = uB.w;
        const int st = 8 >> gg;                // k-bit 3,2,1,0
        #pragma unroll
        for (int k0 = 0; k0 < PER; ++k0) {
            if (k0 & st) continue;             // static under full unroll
            const int k1 = k0 | st;
            const float r0 = ar[k0], m0 = ai[k0];
            const float r1 = ar[k1], m1 = ai[k1];
            ar[k0] = u00r * r0 - u00i * m0 + u01r * r1 - u01i * m1;
            ai[k0] = u00r * m0 + u00i * r0 + u01r * m1 + u01i * r1;
            ar[k1] = u10r * r0 - u10i * m0 + u11r * r1 - u11i * m1;
            ai[k1] = u10r * m0 + u10i * r0 + u11r * m1 + u11i * r1;
        }
    }
}

__global__ __launch_bounds__(THREADS, 2)
void qcirc_kernel(const float* __restrict__ state,
                  const float* __restrict__ weights,
                  const float* __restrict__ head_w,
                  const float* __restrict__ head_b,
                  float* __restrict__ out)
{
    __shared__ float2 buf[PADDED];
    __shared__ __align__(16) float Umat[NGATES][8];
    __shared__ float redbuf[THREADS / 64];

    const int tid = threadIdx.x;
    const int b   = blockIdx.x;

    // ---- 36 gate matrices, one thread each. U = RZ(c)RY(b)RX(a),
    // SU(2): U = [[u00, -conj(u10)], [u10, conj(u00)]].
    if (tid < NGATES) {
        const float* wp = weights + tid * 3;
        float ha = 0.5f * wp[0], hb = 0.5f * wp[1], hc = 0.5f * wp[2];
        float ca = cosf(ha), sa = sinf(ha);
        float cb = cosf(hb), sb = sinf(hb);
        float ecr = cosf(hc), eci = -sinf(hc);   // e^{-i c/2}
        float t0 = cb * ca, t1 = sb * sa, t2 = sb * ca, t3 = cb * sa;
        float u00r =  ecr * t0 - eci * t1;
        float u00i =  ecr * t1 + eci * t0;
        float u10r =  ecr * t2 - eci * t3;
        float u10i = -ecr * t3 - eci * t2;
        Umat[tid][0] =  u00r;  Umat[tid][1] =  u00i;
        Umat[tid][2] = -u10r;  Umat[tid][3] =  u10i;   // U01 = -conj(U10)
        Umat[tid][4] =  u10r;  Umat[tid][5] =  u10i;
        Umat[tid][6] =  u00r;  Umat[tid][7] = -u00i;   // U11 = conj(U00)
    }

    // ---- Initial load into group-A layout: i = (k<<8)|tid  (coalesced).
    float ar[PER], ai[PER];
    {
        const float* sp = state + (size_t)b * DIM;
        #pragma unroll
        for (int k = 0; k < PER; ++k) {
            ar[k] = sp[(k << 8) | tid];
            ai[k] = 0.f;
        }
    }
    __syncthreads();   // Umat ready

    #pragma unroll 1
    for (int l = 0; l < N_LAYERS; ++l) {
        if (l > 0) {
            // Gather previous layer's state through the fused CNOT perm:
            // new[i] = old[i ^ (i>>1)]  (binary->Gray code).
            #pragma unroll
            for (int k = 0; k < PER; ++k) {
                int i = (k << 8) | tid;
                int j = i ^ (i >> 1);
                float2 v = buf[j + (j >> 4)];
                ar[k] = v.x; ai[k] = v.y;
            }
            __syncthreads();   // all gather-reads done before A-writes below
        }

        // Group A: wires 0-3 (i bits 11-8 = k bits 3-0)
        apply4(ar, ai, Umat, l * 12 + 0);
        #pragma unroll
        for (int k = 0; k < PER; ++k) {
            int i = (k << 8) | tid;
            buf[i + (i >> 4)] = make_float2(ar[k], ai[k]);
        }
        __syncthreads();

        // Group B: wires 4-7 (i bits 7-4 = k bits 3-0)
        #pragma unroll
        for (int k = 0; k < PER; ++k) {
            int i = ((tid & 0xF0) << 4) | (k << 4) | (tid & 15);
            float2 v = buf[i + (i >> 4)];
            ar[k] = v.x; ai[k] = v.y;
        }
        apply4(ar, ai, Umat, l * 12 + 4);
        #pragma unroll
        for (int k = 0; k < PER; ++k) {
            int i = ((tid & 0xF0) << 4) | (k << 4) | (tid & 15);
            buf[i + (i >> 4)] = make_float2(ar[k], ai[k]);
        }
        __syncthreads();

        // Group C: wires 8-11 (i bits 3-0 = k bits 3-0)
        #pragma unroll
        for (int k = 0; k < PER; ++k) {
            int i = (tid << 4) | k;
            float2 v = buf[i + (i >> 4)];
            ar[k] = v.x; ai[k] = v.y;
        }
        apply4(ar, ai, Umat, l * 12 + 8);
        if (l < N_LAYERS - 1) {
            #pragma unroll
            for (int k = 0; k < PER; ++k) {
                int i = (tid << 4) | k;
                buf[i + (i >> 4)] = make_float2(ar[k], ai[k]);
            }
            __syncthreads();
        }
    }

    // ---- Measurement. Registers hold pre-perm state at j = (tid<<4)|k;
    // final logical index m = invGray(j) (prefix-xor). Weight
    // c_m = sum_w head_w[w] * (1 - 2*bit_{11-w}(m)); m splits:
    //   bits 11-4 = invGray8(tid) << 4, bits 3-0 = invGray4(k) ^ parity(tid)*0xF.
    float hw[N_WIRES];
    #pragma unroll
    for (int w = 0; w < N_WIRES; ++w) hw[w] = head_w[w];

    int it = tid ^ (tid >> 1); it ^= it >> 2; it ^= it >> 4;  // invGray8(tid)
    float chi = 0.f;
    #pragma unroll
    for (int w = 0; w < 8; ++w)
        chi += ((it >> (7 - w)) & 1) ? -hw[w] : hw[w];
    const int parfill = (__popc(tid) & 1) ? 0xF : 0;

    float acc = 0.f;
    #pragma unroll
    for (int k = 0; k < PER; ++k) {
        int ml = k ^ (k >> 1); ml ^= ml >> 2; ml ^= parfill;  // low 4 bits of m
        float c = chi;
        #pragma unroll
        for (int w = 8; w < 12; ++w)
            c += ((ml >> (11 - w)) & 1) ? -hw[w] : hw[w];
        float p = ar[k] * ar[k] + ai[k] * ai[k];
        acc += p * c;
    }

    #pragma unroll
    for (int off = 32; off > 0; off >>= 1)
        acc += __shfl_down(acc, off, 64);
    if ((tid & 63) == 0) redbuf[tid >> 6] = acc;
    __syncthreads();
    if (tid == 0) {
        float s = 0.f;
        #pragma unroll
        for (int q = 0; q < THREADS / 64; ++q) s += redbuf[q];
        out[b] = s + head_b[0];
    }
}

} // namespace

extern "C" void kernel_launch(void* const* d_in, const int* in_sizes, int n_in,
                              void* d_out, int out_size, void* d_ws, size_t ws_size,
                              hipStream_t stream)
{
    const float* state   = (const float*)d_in[0];  // (B, 4096) fp32
    const float* weights = (const float*)d_in[1];  // (3, 12, 3) fp32
    const float* head_w  = (const float*)d_in[2];  // (1, 12) fp32
    const float* head_b  = (const float*)d_in[3];  // (1,) fp32
    float* out = (float*)d_out;                    // (B,) fp32

    const int batch = in_sizes[0] / DIM;           // 512
    qcirc_kernel<<<batch, THREADS, 0, stream>>>(state, weights, head_w, head_b, out);
}